// Round 8
// baseline (1078.187 us; speedup 1.0000x reference)
//
#include <hip/hip_runtime.h>
#include <math.h>

#define NB 4
#define NV 8
#define NC 32
#define NG 65536
#define IMGW 256
#define NBI 32              // NB*NV
#define RSPLIT 8            // pixel-range split per (b,i)
#define RBINS (NG / RSPLIT) // 8192 bins per range
#define START_STRIDE 65544  // 65536 + sentinel + pad

static constexpr long long STACKED_ELEMS = (long long)NB * NV * NG * NC; // 67108864

// ---------------- ws layout ----------------
// At     : 256 f32                 @ 0
// start  : [bi][65544] u32         @ 4 KB     (8.39 MB)
// cnt    : [bi][65536] u32         @ +8.39 MB (8.39 MB)
// pixarr : [bi][j][g] u16          @ +16.8 MB (33.6 MB)
// sorted : [bi][slot] u32 (1<<19)  @ +50.3 MB (67.1 MB)  payload m = (j<<16)|g
// fb16   : [b][j][g][c] bf16       @ +117.4MB (134.2 MB)
static constexpr size_t OFF_AT    = 0;
static constexpr size_t OFF_START = 4096;
static constexpr size_t OFF_CNT   = OFF_START + (size_t)NBI * START_STRIDE * 4;
static constexpr size_t OFF_PIX   = OFF_CNT + (size_t)NBI * NG * 4;
static constexpr size_t OFF_SORT  = OFF_PIX + (size_t)NBI * NV * NG * 2;
static constexpr size_t OFF_FB16  = OFF_SORT + (size_t)NBI * (1u << 19) * 4;

// ---------------- adjacency ----------------
__global__ __launch_bounds__(256) void adj_kernel(const float* __restrict__ ext,
                                                  float* __restrict__ A_out,
                                                  float* __restrict__ At_out)
{
    __shared__ float ctr[NB * NV][3];
    __shared__ float Dsh[NB * NV * NV];
    int t = threadIdx.x;
    if (t < NB * NV) {
        const float* E = ext + t * 16;
        #pragma unroll
        for (int i = 0; i < 3; i++) {
            float s = E[0 * 4 + i] * E[0 * 4 + 3]
                    + E[1 * 4 + i] * E[1 * 4 + 3]
                    + E[2 * 4 + i] * E[2 * 4 + 3];
            ctr[t][i] = -s;
        }
    }
    __syncthreads();
    {
        int b = t >> 6, i = (t >> 3) & 7, j = t & 7;
        float dx = ctr[b * 8 + i][0] - ctr[b * 8 + j][0];
        float dy = ctr[b * 8 + i][1] - ctr[b * 8 + j][1];
        float dz = ctr[b * 8 + i][2] - ctr[b * 8 + j][2];
        Dsh[t] = dx * dx + dy * dy + dz * dz;
    }
    __syncthreads();
    if (t < NB * NV) {
        int ri = t & 7;
        const float* drow = &Dsh[t * 8];
        bool chosen[8] = {false, false, false, false, false, false, false, false};
        for (int n = 0; n < 3; n++) {
            int best = -1; float bs = -3.0e38f;
            for (int j2 = 0; j2 < 8; j2++) {
                if (j2 == ri || chosen[j2]) continue;
                float s = -drow[j2];
                if (s > bs) { bs = s; best = j2; }
            }
            chosen[best] = true;
        }
        float row[8]; float deg = 0.f;
        #pragma unroll
        for (int j2 = 0; j2 < 8; j2++) {
            float a = 0.f;
            if (j2 == ri)        a = 1.0f;
            else if (chosen[j2]) a = 1.0f / (1.0f + sqrtf(drow[j2] + 1e-6f));
            row[j2] = a; deg += a;
        }
        float dn = deg + (deg == 0.f ? 1.f : 0.f);
        #pragma unroll
        for (int j2 = 0; j2 < 8; j2++) {
            A_out[t * 8 + j2]  = row[j2];
            At_out[t * 8 + j2] = row[j2] / dn;
        }
    }
}

// ---------------- kf: features f32 -> bf16 (RNE), streaming ----------------
__device__ __forceinline__ unsigned short f2bf(float f)
{
    unsigned int u = __float_as_uint(f);
    return (unsigned short)((u + 0x7FFFu + ((u >> 16) & 1u)) >> 16);
}

__global__ __launch_bounds__(256) void kf_conv(const float4* __restrict__ feat4,
                                               ushort4* __restrict__ fb16)
{
    unsigned int base = blockIdx.x * 1024 + threadIdx.x; // 4 chunks of 256; 16,777,216 float4s
    #pragma unroll
    for (int k = 0; k < 4; k++) {
        unsigned int tid = base + k * 256;
        float4 v = feat4[tid];
        ushort4 o;
        o.x = f2bf(v.x); o.y = f2bf(v.y); o.z = f2bf(v.z); o.w = f2bf(v.w);
        fb16[tid] = o;
    }
}

// ---------------- k1: pixel precompute (pure streaming, no atomics) ----------------
__global__ __launch_bounds__(256) void k1_pix(const float2* __restrict__ xy,
                                              unsigned short* __restrict__ pixarr)
{
    unsigned int base = blockIdx.x * 1024 + threadIdx.x; // 4 chunks of 256
    #pragma unroll
    for (int k = 0; k < 4; k++) {
        unsigned int tid = base + k * 256; // [b][j][i][g]
        float2 p = xy[tid];
        float px = fminf(fmaxf(rintf(p.x), 0.f), (float)(IMGW - 1));
        float py = fminf(fmaxf(rintf(p.y), 0.f), (float)(IMGW - 1));
        unsigned int pix = (unsigned int)py * IMGW + (unsigned int)px;
        unsigned int g = tid & 0xFFFFu;
        unsigned int i = (tid >> 16) & 7u;
        unsigned int j = (tid >> 19) & 7u;
        unsigned int b = tid >> 22;
        unsigned int bi = (b << 3) | i;
        pixarr[(((bi << 3) | j) << 16) | g] = (unsigned short)pix; // [bi][j][g]
    }
}

// ---------------- k2: LDS histogram per (bi, pixel-range) ----------------
__global__ __launch_bounds__(1024) void k2_hist(const unsigned short* __restrict__ pixarr,
                                                unsigned int* __restrict__ cnt)
{
    __shared__ unsigned int hist[RBINS]; // 32 KB
    int t = threadIdx.x;
    unsigned int bi = blockIdx.x >> 3;
    unsigned int r  = blockIdx.x & 7u;
    unsigned int r0 = r * RBINS;
    for (int k = t; k < RBINS; k += 1024) hist[k] = 0;
    __syncthreads();
    const uint4* src = (const uint4*)(pixarr + ((size_t)bi << 19)); // 64K uint4
    for (int it = 0; it < 64; it++) {
        uint4 v = src[t + it * 1024];
        const unsigned int* vw = (const unsigned int*)&v;
        #pragma unroll
        for (int h = 0; h < 4; h++) {
            unsigned int w = vw[h];
            unsigned int p0 = (w & 0xFFFFu) - r0;
            unsigned int p1 = (w >> 16) - r0;
            if (p0 < RBINS) atomicAdd(&hist[p0], 1u);
            if (p1 < RBINS) atomicAdd(&hist[p1], 1u);
        }
    }
    __syncthreads();
    unsigned int* dst = cnt + ((size_t)bi << 16) + r0;
    for (int k = t; k < RBINS; k += 1024) dst[k] = hist[k];
}

// ---------------- k3: exclusive scan per bi -> start[] + sentinel ----------------
__global__ __launch_bounds__(1024) void k3_scan(const unsigned int* __restrict__ cnt,
                                                unsigned int* __restrict__ start)
{
    __shared__ unsigned int lds[1024];
    int bi = blockIdx.x;
    const unsigned int* c = cnt + ((size_t)bi << 16);
    unsigned int* st = start + (size_t)bi * START_STRIDE;
    int t = threadIdx.x;
    unsigned int s = 0;
    for (int k = 0; k < 64; k++) s += c[t * 64 + k];
    lds[t] = s;
    __syncthreads();
    for (int off = 1; off < 1024; off <<= 1) {
        unsigned int v = (t >= off) ? lds[t - off] : 0u;
        __syncthreads();
        lds[t] += v;
        __syncthreads();
    }
    unsigned int run = lds[t] - s;
    for (int k = 0; k < 64; k++) {
        unsigned int cv = c[t * 64 + k];
        st[t * 64 + k] = run;
        run += cv;
    }
    if (t == 1023) st[NG] = run; // sentinel = 512K
}

// ---------------- k4: counting-sort fill via LDS cursors (no global atomics) ----------------
__global__ __launch_bounds__(1024) void k4_fill(const unsigned short* __restrict__ pixarr,
                                                const unsigned int* __restrict__ start,
                                                unsigned int* __restrict__ sorted)
{
    __shared__ unsigned int cur[RBINS]; // 32 KB, init = absolute start
    int t = threadIdx.x;
    unsigned int bi = blockIdx.x >> 3;
    unsigned int r  = blockIdx.x & 7u;
    unsigned int r0 = r * RBINS;
    const unsigned int* st = start + (size_t)bi * START_STRIDE + r0;
    for (int k = t; k < RBINS; k += 1024) cur[k] = st[k];
    __syncthreads();
    const uint4* src = (const uint4*)(pixarr + ((size_t)bi << 19));
    unsigned int* dstbase = sorted + ((size_t)bi << 19);
    for (int it = 0; it < 64; it++) {
        unsigned int m0 = (t + it * 1024) * 8;
        uint4 v = src[t + it * 1024];
        const unsigned int* vw = (const unsigned int*)&v;
        #pragma unroll
        for (int h = 0; h < 8; h++) {
            unsigned int w = vw[h >> 1];
            unsigned int pv = ((h & 1) ? (w >> 16) : (w & 0xFFFFu)) - r0;
            if (pv < RBINS) {
                unsigned int slot = atomicAdd(&cur[pv], 1u); // LDS atomic
                dstbase[slot] = m0 + h; // payload m = (j<<16)|g
            }
        }
    }
}

// ---------------- b_gather: bf16 rows, aligned uint4 payloads, nt out ----------------
// 32-lane group per output row (b,i,g); lane c owns channel c.
__global__ __launch_bounds__(256) void b_gather(
    const unsigned short* __restrict__ fb16,   // [b][j][g][c] bf16
    const unsigned short* __restrict__ pixarr,
    const unsigned int* __restrict__ start,
    const unsigned int* __restrict__ sorted,
    const float* __restrict__ Wlin,
    const float* __restrict__ blin,
    const float* __restrict__ At,
    float* __restrict__ out)
{
    __shared__ float At_s[NB * NV * NV];
    int t = threadIdx.x;
    int c = t & 31;
    int grp = t >> 5;

    unsigned int rrow = blockIdx.x * 8 + grp; // [bi][g]
    unsigned int g = rrow & 0xFFFFu;
    unsigned int bi = rrow >> 16;
    unsigned int i = bi & 7u;
    unsigned int b = bi >> 3;
    unsigned int pix = pixarr[(((bi << 3) | i) << 16) | g]; // diag pixel

    At_s[t] = At[t];

    const unsigned int* st = start + (size_t)bi * START_STRIDE;
    unsigned int s0 = st[pix];
    unsigned int e0 = st[pix + 1];
    const unsigned int* pl = sorted + ((size_t)bi << 19);
    const unsigned short* fb = fb16 + ((size_t)b << 19) * NC; // b slab (bf16)
    __syncthreads();

    const float* Atrow = &At_s[bi << 3];
    float acc = 0.f, wsum = 0.f;
    unsigned int k0a = s0 & ~7u; // align chunk start for uint4 payload loads
    for (unsigned int k0 = k0a; k0 < e0; k0 += 8) {
        uint4 pa = *(const uint4*)(pl + k0);
        uint4 pb = *(const uint4*)(pl + k0 + 4);
        unsigned int pv[8] = {pa.x, pa.y, pa.z, pa.w, pb.x, pb.y, pb.z, pb.w};
        unsigned int uv[8];
        #pragma unroll
        for (int h = 0; h < 8; h++) {
            unsigned int idx = pv[h] & 0x7FFFFu;         // (j<<16)|g, masked for pad safety
            uv[h] = fb[idx * NC + c];                    // 32-bit saddr offset, 64 B/row
        }
        #pragma unroll
        for (int h = 0; h < 8; h++) {
            unsigned int kk = k0 + h;
            float w = (kk >= s0 && kk < e0) ? Atrow[(pv[h] >> 16) & 7u] : 0.f;
            float fvf = __uint_as_float(uv[h] << 16);    // bf16 -> f32
            acc = fmaf(w, fvf, acc);
            wsum += w;
        }
    }

    // epilogue: deferred 32x32 linear via shuffles
    float o;
    {
        float bias = blin[c];
        o = bias * wsum;
        #pragma unroll
        for (int k = 0; k < NC; k++) {
            float wc = Wlin[k * NC + c];
            o = fmaf(__shfl(acc, k, 32), wc, o);
        }
    }
    __builtin_nontemporal_store(o, &out[(((size_t)bi << 16) | g) * NC + c]);
}

extern "C" void kernel_launch(void* const* d_in, const int* in_sizes, int n_in,
                              void* d_out, int out_size, void* d_ws, size_t ws_size,
                              hipStream_t stream)
{
    const float* features = (const float*)d_in[0];
    const float* xy       = (const float*)d_in[1];
    const float* ext      = (const float*)d_in[2];
    const float* Wlin     = (const float*)d_in[3];
    const float* blin     = (const float*)d_in[4];
    float* out = (float*)d_out;

    char* ws = (char*)d_ws;
    float*          At     = (float*)(ws + OFF_AT);
    unsigned int*   start  = (unsigned int*)(ws + OFF_START);
    unsigned int*   cnt    = (unsigned int*)(ws + OFF_CNT);
    unsigned short* pixarr = (unsigned short*)(ws + OFF_PIX);
    unsigned int*   sorted = (unsigned int*)(ws + OFF_SORT);
    unsigned short* fb16   = (unsigned short*)(ws + OFF_FB16);

    adj_kernel<<<1, 256, 0, stream>>>(ext, out + STACKED_ELEMS, At);

    kf_conv<<<(NB * NV * NG * NC / 4) / 1024, 256, 0, stream>>>(
        (const float4*)features, (ushort4*)fb16);
    k1_pix<<<(NB * NV * NV * NG) / 1024, 256, 0, stream>>>((const float2*)xy, pixarr);
    k2_hist<<<NBI * RSPLIT, 1024, 0, stream>>>(pixarr, cnt);
    k3_scan<<<NBI, 1024, 0, stream>>>(cnt, start);
    k4_fill<<<NBI * RSPLIT, 1024, 0, stream>>>(pixarr, start, sorted);

    const int nrows_blocks = (NB * NV * NG) / 8;
    b_gather<<<nrows_blocks, 256, 0, stream>>>(fb16, pixarr, start, sorted,
                                               Wlin, blin, At, out);
}

// Round 9
// 986.908 us; speedup vs baseline: 1.0925x; 1.0925x over previous
//
#include <hip/hip_runtime.h>
#include <math.h>

#define NB 4
#define NV 8
#define NC 32
#define NG 65536
#define IMGW 256
#define NBI 32               // NB*NV
#define RSPLIT 8             // pixel-range split per (b,i)
#define RBINS (NG / RSPLIT)  // 8192 bins per range
#define START_STRIDE 65544   // 65536 + sentinel + pad
#define SORT_STRIDE (1u << 20) // padded slot capacity per bi
#define SENTINEL 0x80000u    // windex=8 (w=0); row idx masks to 0

static constexpr long long STACKED_ELEMS = (long long)NB * NV * NG * NC; // 67108864

// ---------------- ws layout ----------------
// At     : 256 f32                     @ 0
// start  : [bi][65544] u32 (PADDED)    @ 4 KB     (8.39 MB)  8-aligned starts + sentinel
// cnt    : [bi][65536] u32             @ +8.39 MB (8.39 MB)
// pixarr : [bi][j][g] u16              @ +16.8 MB (33.6 MB)
// sorted : [bi][slot] u32 (1<<20 ea)   @ +50.3 MB (134 MB)   payload m=(j<<16)|g or SENTINEL
static constexpr size_t OFF_AT    = 0;
static constexpr size_t OFF_START = 4096;
static constexpr size_t OFF_CNT   = OFF_START + (size_t)NBI * START_STRIDE * 4;
static constexpr size_t OFF_PIX   = OFF_CNT + (size_t)NBI * NG * 4;
static constexpr size_t OFF_SORT  = OFF_PIX + (size_t)NBI * NV * NG * 2;

// ---------------- adjacency ----------------
__global__ __launch_bounds__(256) void adj_kernel(const float* __restrict__ ext,
                                                  float* __restrict__ A_out,
                                                  float* __restrict__ At_out)
{
    __shared__ float ctr[NB * NV][3];
    __shared__ float Dsh[NB * NV * NV];
    int t = threadIdx.x;
    if (t < NB * NV) {
        const float* E = ext + t * 16;
        #pragma unroll
        for (int i = 0; i < 3; i++) {
            float s = E[0 * 4 + i] * E[0 * 4 + 3]
                    + E[1 * 4 + i] * E[1 * 4 + 3]
                    + E[2 * 4 + i] * E[2 * 4 + 3];
            ctr[t][i] = -s;
        }
    }
    __syncthreads();
    {
        int b = t >> 6, i = (t >> 3) & 7, j = t & 7;
        float dx = ctr[b * 8 + i][0] - ctr[b * 8 + j][0];
        float dy = ctr[b * 8 + i][1] - ctr[b * 8 + j][1];
        float dz = ctr[b * 8 + i][2] - ctr[b * 8 + j][2];
        Dsh[t] = dx * dx + dy * dy + dz * dz;
    }
    __syncthreads();
    if (t < NB * NV) {
        int ri = t & 7;
        const float* drow = &Dsh[t * 8];
        bool chosen[8] = {false, false, false, false, false, false, false, false};
        for (int n = 0; n < 3; n++) {
            int best = -1; float bs = -3.0e38f;
            for (int j2 = 0; j2 < 8; j2++) {
                if (j2 == ri || chosen[j2]) continue;
                float s = -drow[j2];
                if (s > bs) { bs = s; best = j2; }
            }
            chosen[best] = true;
        }
        float row[8]; float deg = 0.f;
        #pragma unroll
        for (int j2 = 0; j2 < 8; j2++) {
            float a = 0.f;
            if (j2 == ri)        a = 1.0f;
            else if (chosen[j2]) a = 1.0f / (1.0f + sqrtf(drow[j2] + 1e-6f));
            row[j2] = a; deg += a;
        }
        float dn = deg + (deg == 0.f ? 1.f : 0.f);
        #pragma unroll
        for (int j2 = 0; j2 < 8; j2++) {
            A_out[t * 8 + j2]  = row[j2];
            At_out[t * 8 + j2] = row[j2] / dn;
        }
    }
}

// ---------------- k1: pixel precompute (pure streaming, no atomics) ----------------
__global__ __launch_bounds__(256) void k1_pix(const float2* __restrict__ xy,
                                              unsigned short* __restrict__ pixarr)
{
    unsigned int base = blockIdx.x * 1024 + threadIdx.x; // 4 chunks of 256
    #pragma unroll
    for (int k = 0; k < 4; k++) {
        unsigned int tid = base + k * 256; // [b][j][i][g]
        float2 p = xy[tid];
        float px = fminf(fmaxf(rintf(p.x), 0.f), (float)(IMGW - 1));
        float py = fminf(fmaxf(rintf(p.y), 0.f), (float)(IMGW - 1));
        unsigned int pix = (unsigned int)py * IMGW + (unsigned int)px;
        unsigned int g = tid & 0xFFFFu;
        unsigned int i = (tid >> 16) & 7u;
        unsigned int j = (tid >> 19) & 7u;
        unsigned int b = tid >> 22;
        unsigned int bi = (b << 3) | i;
        pixarr[(((bi << 3) | j) << 16) | g] = (unsigned short)pix; // [bi][j][g]
    }
}

// ---------------- k2: LDS histogram per (bi, pixel-range) ----------------
__global__ __launch_bounds__(1024) void k2_hist(const unsigned short* __restrict__ pixarr,
                                                unsigned int* __restrict__ cnt)
{
    __shared__ unsigned int hist[RBINS]; // 32 KB
    int t = threadIdx.x;
    unsigned int bi = blockIdx.x >> 3;
    unsigned int r  = blockIdx.x & 7u;
    unsigned int r0 = r * RBINS;
    for (int k = t; k < RBINS; k += 1024) hist[k] = 0;
    __syncthreads();
    const uint4* src = (const uint4*)(pixarr + ((size_t)bi << 19)); // 64K uint4
    for (int it = 0; it < 64; it++) {
        uint4 v = src[t + it * 1024];
        const unsigned int* vw = (const unsigned int*)&v;
        #pragma unroll
        for (int h = 0; h < 4; h++) {
            unsigned int w = vw[h];
            unsigned int p0 = (w & 0xFFFFu) - r0;
            unsigned int p1 = (w >> 16) - r0;
            if (p0 < RBINS) atomicAdd(&hist[p0], 1u);
            if (p1 < RBINS) atomicAdd(&hist[p1], 1u);
        }
    }
    __syncthreads();
    unsigned int* dst = cnt + ((size_t)bi << 16) + r0;
    for (int k = t; k < RBINS; k += 1024) dst[k] = hist[k];
}

// ---------------- k3: exclusive scan of PADDED counts -> 8-aligned starts ----------------
__global__ __launch_bounds__(1024) void k3_scan(const unsigned int* __restrict__ cnt,
                                                unsigned int* __restrict__ start)
{
    __shared__ unsigned int lds[1024];
    int bi = blockIdx.x;
    const unsigned int* c = cnt + ((size_t)bi << 16);
    unsigned int* st = start + (size_t)bi * START_STRIDE;
    int t = threadIdx.x;
    unsigned int s = 0;
    for (int k = 0; k < 64; k++) s += (c[t * 64 + k] + 7u) & ~7u;
    lds[t] = s;
    __syncthreads();
    for (int off = 1; off < 1024; off <<= 1) {
        unsigned int v = (t >= off) ? lds[t - off] : 0u;
        __syncthreads();
        lds[t] += v;
        __syncthreads();
    }
    unsigned int run = lds[t] - s;
    for (int k = 0; k < 64; k++) {
        unsigned int cv = (c[t * 64 + k] + 7u) & ~7u;
        st[t * 64 + k] = run;
        run += cv;
    }
    if (t == 1023) st[NG] = run; // sentinel
}

// ---------------- k4: counting-sort fill + sentinel padding (LDS cursors) ----------------
__global__ __launch_bounds__(1024) void k4_fill(const unsigned short* __restrict__ pixarr,
                                                const unsigned int* __restrict__ start,
                                                unsigned int* __restrict__ sorted)
{
    __shared__ unsigned int cur[RBINS]; // 32 KB, init = padded start
    int t = threadIdx.x;
    unsigned int bi = blockIdx.x >> 3;
    unsigned int r  = blockIdx.x & 7u;
    unsigned int r0 = r * RBINS;
    const unsigned int* stg = start + (size_t)bi * START_STRIDE;
    for (int k = t; k < RBINS; k += 1024) cur[k] = stg[r0 + k];
    __syncthreads();
    const uint4* src = (const uint4*)(pixarr + ((size_t)bi << 19));
    unsigned int* dstbase = sorted + (size_t)bi * SORT_STRIDE;
    for (int it = 0; it < 64; it++) {
        unsigned int m0 = (t + it * 1024) * 8;
        uint4 v = src[t + it * 1024];
        const unsigned int* vw = (const unsigned int*)&v;
        #pragma unroll
        for (int h = 0; h < 8; h++) {
            unsigned int w = vw[h >> 1];
            unsigned int pv = ((h & 1) ? (w >> 16) : (w & 0xFFFFu)) - r0;
            if (pv < RBINS) {
                unsigned int slot = atomicAdd(&cur[pv], 1u); // LDS atomic
                dstbase[slot] = m0 + h; // payload m = (j<<16)|g
            }
        }
    }
    __syncthreads();
    // pad each bin up to the next bin's (padded) start
    for (int k = t; k < RBINS; k += 1024) {
        unsigned int e = stg[r0 + k + 1];
        for (unsigned int x = cur[k]; x < e; x++) dstbase[x] = SENTINEL;
    }
}

// ---------------- b_gather: mask-free 8-wide gather + deferred linear ----------------
// 32-lane group per output row (b,i,g); lane c owns channel c.
// Bins are 8-padded with SENTINEL (windex 8 -> w=0, row idx -> 0): no compares.
__global__ __launch_bounds__(256) void b_gather(
    const float* __restrict__ feat,            // raw f32 features (B,V,G,C)
    const unsigned short* __restrict__ pixarr,
    const unsigned int* __restrict__ start,
    const unsigned int* __restrict__ sorted,
    const float* __restrict__ Wlin,
    const float* __restrict__ blin,
    const float* __restrict__ At,
    float* __restrict__ out)
{
    __shared__ float At9[NBI][16]; // 9-wide weight rows (index 8 = 0.0), padded stride
    int t = threadIdx.x;
    int c = t & 31;
    int grp = t >> 5;

    unsigned int rrow = blockIdx.x * 8 + grp; // [bi][g]
    unsigned int g = rrow & 0xFFFFu;
    unsigned int bi = rrow >> 16;
    unsigned int i = bi & 7u;
    unsigned int b = bi >> 3;
    unsigned int pix = pixarr[(((bi << 3) | i) << 16) | g]; // diag pixel

    At9[t >> 3][t & 7] = At[t];
    At9[t >> 3][8 + (t & 7)] = 0.f;

    const unsigned int* st = start + (size_t)bi * START_STRIDE;
    unsigned int s0 = st[pix];     // 8-aligned
    unsigned int e0 = st[pix + 1]; // padded end
    const unsigned int* pl = sorted + (size_t)bi * SORT_STRIDE;
    const float* featb = feat + (((size_t)b) << 19) * NC; // feat[b]
    __syncthreads();

    const float* Atrow = At9[bi];
    float acc = 0.f, wsum = 0.f;
    for (unsigned int k0 = s0; k0 < e0; k0 += 8) {
        uint4 pa = *(const uint4*)(pl + k0);
        uint4 pb = *(const uint4*)(pl + k0 + 4);
        unsigned int pv[8] = {pa.x, pa.y, pa.z, pa.w, pb.x, pb.y, pb.z, pb.w};
        #pragma unroll
        for (int h = 0; h < 8; h++) {
            float fv = featb[(size_t)(pv[h] & 0x7FFFFu) * NC + c]; // sentinel -> row 0
            float w = Atrow[pv[h] >> 16];                          // sentinel -> 0.0
            acc = fmaf(w, fv, acc);
            wsum += w;
        }
    }

    // epilogue: deferred 32x32 linear via shuffles
    float bias = blin[c];
    float o = bias * wsum;
    #pragma unroll
    for (int k = 0; k < NC; k++)
        o = fmaf(__shfl(acc, k, 32), Wlin[k * NC + c], o);
    __builtin_nontemporal_store(o, &out[(((size_t)bi << 16) | g) * NC + c]);
}

extern "C" void kernel_launch(void* const* d_in, const int* in_sizes, int n_in,
                              void* d_out, int out_size, void* d_ws, size_t ws_size,
                              hipStream_t stream)
{
    const float* features = (const float*)d_in[0];
    const float* xy       = (const float*)d_in[1];
    const float* ext      = (const float*)d_in[2];
    const float* Wlin     = (const float*)d_in[3];
    const float* blin     = (const float*)d_in[4];
    float* out = (float*)d_out;

    char* ws = (char*)d_ws;
    float*          At     = (float*)(ws + OFF_AT);
    unsigned int*   start  = (unsigned int*)(ws + OFF_START);
    unsigned int*   cnt    = (unsigned int*)(ws + OFF_CNT);
    unsigned short* pixarr = (unsigned short*)(ws + OFF_PIX);
    unsigned int*   sorted = (unsigned int*)(ws + OFF_SORT);

    adj_kernel<<<1, 256, 0, stream>>>(ext, out + STACKED_ELEMS, At);

    k1_pix<<<(NB * NV * NV * NG) / 1024, 256, 0, stream>>>((const float2*)xy, pixarr);
    k2_hist<<<NBI * RSPLIT, 1024, 0, stream>>>(pixarr, cnt);
    k3_scan<<<NBI, 1024, 0, stream>>>(cnt, start);
    k4_fill<<<NBI * RSPLIT, 1024, 0, stream>>>(pixarr, start, sorted);

    const int nrows_blocks = (NB * NV * NG) / 8;
    b_gather<<<nrows_blocks, 256, 0, stream>>>(features, pixarr, start, sorted,
                                               Wlin, blin, At, out);
}